// Round 7
// baseline (474.701 us; speedup 1.0000x reference)
//
#include <hip/hip_runtime.h>
#include <math.h>

#define GPB 8        // 32-lane groups per 256-thread block
#define EPG 2        // batch elements per group (register blocking)
#define THREADS 256

// ---- 16-lane-row sum via DPP row rotates (VALU pipe, no LDS) ----
template<int CTRL>
__device__ __forceinline__ float dpp_add(float x) {
    int xi = __builtin_bit_cast(int, x);
    int yi = __builtin_amdgcn_update_dpp(0, xi, CTRL, 0xF, 0xF, false);
    return x + __builtin_bit_cast(float, yi);
}
__device__ __forceinline__ float row16_sum(float x) {
    x = dpp_add<0x121>(x);  // row_ror:1
    x = dpp_add<0x122>(x);  // row_ror:2
    x = dpp_add<0x124>(x);  // row_ror:4
    x = dpp_add<0x128>(x);  // row_ror:8
    return x;
}
// ---- exchange-with-lane^16 within the 32-lane group, then add ----
__device__ __forceinline__ float xor16_add(float x) {
    int y = __builtin_amdgcn_ds_swizzle(__builtin_bit_cast(int, x), 0x401F);
    return x + __builtin_bit_cast(float, y);
}
__device__ __forceinline__ float rcpf_(float x) { return __builtin_amdgcn_rcpf(x); }

// ---- setup: W[7,12,8,16] -> Wt[((n*8+j)*2+q)*32 + l] float4, l=(kh,t) ----
__global__ void transpose_W_kernel(const float* __restrict__ W,
                                   float4* __restrict__ Wt) {
    int i = blockIdx.x * blockDim.x + threadIdx.x;   // 7*8*2*32 = 3584
    if (i < 3584) {
        int l  = i & 31;
        int r  = i >> 5;          // (n*8+j)*2 + q
        int q  = r & 1;
        int j  = (r >> 1) & 7;
        int n  = r >> 4;
        int kh = l >> 4;
        int t  = l & 15;
        int mm = (t < 12) ? t : 11;
        const float* src = W + (((size_t)(n * 12 + mm) * 8 + j) * 16 + kh * 8 + q * 4);
        Wt[i] = *(const float4*)src;
    }
}

// 32 lanes per group, 2 batch elements per group. lane = (kh, t):
// kh = k-half owned for BOTH elements; t = output capsule m (12 active).
__global__ __launch_bounds__(THREADS) void capsnet_kernel(
    const float* __restrict__ x,      // [B,210]
    const float* __restrict__ W_pc,   // [7,8,30]
    const float* __restrict__ b_pc,   // [7,8]
    const float4* __restrict__ Wt,    // transposed W
    const int*  __restrict__ p_niter,
    float* __restrict__ out,          // [B,12]
    int B)
{
    __shared__ float xs[GPB][420];        // two adjacent x rows per group
    __shared__ float us[GPB][EPG][56];    // primary capsules

    const int tid = threadIdx.x;
    const int g   = tid >> 5;
    const int l   = tid & 31;
    const int kh  = l >> 4;
    const int t   = l & 15;
    int b0 = (blockIdx.x * GPB + g) * EPG;
    if (b0 + 1 >= B) b0 = B - 2;          // clamp; duplicate groups write identical values
    const int niter = *p_niter;

    // ---- stage x[b0], x[b0+1] (contiguous: 210 float2) into LDS ----
    {
        const float2* xrow = (const float2*)(x + (size_t)b0 * 210);
        float2* xdst = (float2*)&xs[g][0];
        #pragma unroll
        for (int i = 0; i < 7; ++i) {
            int idx = l + 32 * i;
            if (idx < 210) xdst[idx] = xrow[idx];
        }
    }
    __syncthreads();

    // ---- primary capsules for both elements ----
    #pragma unroll
    for (int e = 0; e < EPG; ++e) {
        #pragma unroll
        for (int i = 0; i < 2; ++i) {
            int idx = l + 32 * i;             // n*8 + o, 56 outputs
            if (idx < 56) {
                int n = idx >> 3;
                const float2* wrow2 = (const float2*)(W_pc + idx * 30);
                const float2* xr2   = (const float2*)&xs[g][e * 210 + n * 30];
                float acc = b_pc[idx];
                #pragma unroll
                for (int gg = 0; gg < 15; ++gg) {
                    float2 wv = wrow2[gg];
                    float2 xv = xr2[gg];
                    acc += xv.x * wv.x;
                    acc += xv.y * wv.y;
                }
                us[g][e][idx] = acc;
            }
        }
    }
    __syncthreads();

    // ---- squash primary capsules: lanes 0..6 -> e=0, lanes 16..22 -> e=1 ----
    {
        int sn = l & 15;
        int se = l >> 4;
        if (sn < 7) {
            float vals[8];
            float s2 = 0.f;
            #pragma unroll
            for (int o = 0; o < 8; ++o) {
                vals[o] = us[g][se][sn * 8 + o];
                s2 += vals[o] * vals[o];
            }
            float nrm = sqrtf(s2);
            float f = nrm * rcpf_((1.f + s2) * (nrm + 1e-8f));
            #pragma unroll
            for (int o = 0; o < 8; ++o) us[g][se][sn * 8 + o] = vals[o] * f;
        }
    }
    __syncthreads();

    // ---- u_hat[e][n][kk]: Wt loads shared across both elements ----
    float uh[EPG][7][8];
    #pragma unroll
    for (int n = 0; n < 7; ++n) {
        float uu[EPG][8];
        #pragma unroll
        for (int e = 0; e < EPG; ++e) {
            float4 a  = *(const float4*)&us[g][e][n * 8];
            float4 c4 = *(const float4*)&us[g][e][n * 8 + 4];
            uu[e][0] = a.x;  uu[e][1] = a.y;  uu[e][2] = a.z;  uu[e][3] = a.w;
            uu[e][4] = c4.x; uu[e][5] = c4.y; uu[e][6] = c4.z; uu[e][7] = c4.w;
        }
        #pragma unroll
        for (int e = 0; e < EPG; ++e)
            #pragma unroll
            for (int kk = 0; kk < 8; ++kk) uh[e][n][kk] = 0.f;
        #pragma unroll
        for (int j = 0; j < 8; ++j) {
            const float4* base = Wt + (size_t)(n * 8 + j) * 64 + l;
            float4 w0 = base[0];    // k = kh*8 + 0..3
            float4 w1 = base[32];   // k = kh*8 + 4..7
            #pragma unroll
            for (int e = 0; e < EPG; ++e) {
                float uj = uu[e][j];
                uh[e][n][0] += uj * w0.x;  uh[e][n][1] += uj * w0.y;
                uh[e][n][2] += uj * w0.z;  uh[e][n][3] += uj * w0.w;
                uh[e][n][4] += uj * w1.x;  uh[e][n][5] += uj * w1.y;
                uh[e][n][6] += uj * w1.z;  uh[e][n][7] += uj * w1.w;
            }
        }
    }

    // ---- dynamic routing (two independent chains, interleaved) ----
    const bool active = (t < 12);
    float blog[EPG][7];
    float vnorm[EPG];
    #pragma unroll
    for (int e = 0; e < EPG; ++e) vnorm[e] = 0.f;

    // iteration 0: b == 0 => c == 1/12 exactly
    {
        #pragma unroll
        for (int e = 0; e < EPG; ++e) {
            float s[8];
            #pragma unroll
            for (int kk = 0; kk < 8; ++kk) s[kk] = uh[e][0][kk];
            #pragma unroll
            for (int n = 1; n < 7; ++n)
                #pragma unroll
                for (int kk = 0; kk < 8; ++kk) s[kk] += uh[e][n][kk];
            const float c0 = 1.0f / 12.0f;
            #pragma unroll
            for (int kk = 0; kk < 8; ++kk) s[kk] *= c0;
            float s2l = 0.f;
            #pragma unroll
            for (int kk = 0; kk < 8; ++kk) s2l += s[kk] * s[kk];
            float s2 = xor16_add(s2l);
            float nrm = sqrtf(s2);
            float f = nrm * rcpf_((1.f + s2) * (nrm + 1e-8f));
            if (niter == 1) {
                vnorm[e] = f * nrm;
            } else {
                #pragma unroll
                for (int kk = 0; kk < 8; ++kk) s[kk] *= f;
                #pragma unroll
                for (int n = 0; n < 7; ++n) {
                    float dl = 0.f;
                    #pragma unroll
                    for (int kk = 0; kk < 8; ++kk) dl += uh[e][n][kk] * s[kk];
                    blog[e][n] = xor16_add(dl);
                }
            }
        }
    }

    for (int it = 1; it < niter; ++it) {
        #pragma unroll
        for (int e = 0; e < EPG; ++e) {
            float c[7];
            #pragma unroll
            for (int n = 0; n < 7; ++n) {
                float ev = active ? __expf(blog[e][n]) : 0.f;
                float sm = row16_sum(ev);
                c[n] = ev * rcpf_(sm);
            }
            float s[8];
            #pragma unroll
            for (int kk = 0; kk < 8; ++kk) s[kk] = 0.f;
            #pragma unroll
            for (int n = 0; n < 7; ++n) {
                float cn = c[n];
                #pragma unroll
                for (int kk = 0; kk < 8; ++kk) s[kk] += cn * uh[e][n][kk];
            }
            float s2l = 0.f;
            #pragma unroll
            for (int kk = 0; kk < 8; ++kk) s2l += s[kk] * s[kk];
            float s2 = xor16_add(s2l);
            float nrm = sqrtf(s2);
            float f = nrm * rcpf_((1.f + s2) * (nrm + 1e-8f));
            if (it == niter - 1) {
                vnorm[e] = f * nrm;
            } else {
                #pragma unroll
                for (int kk = 0; kk < 8; ++kk) s[kk] *= f;
                #pragma unroll
                for (int n = 0; n < 7; ++n) {
                    float dl = 0.f;
                    #pragma unroll
                    for (int kk = 0; kk < 8; ++kk) dl += uh[e][n][kk] * s[kk];
                    blog[e][n] += xor16_add(dl);
                }
            }
        }
    }

    if (active && (kh == 0)) {
        #pragma unroll
        for (int e = 0; e < EPG; ++e)
            out[(size_t)(b0 + e) * 12 + t] = vnorm[e];
    }
}

extern "C" void kernel_launch(void* const* d_in, const int* in_sizes, int n_in,
                              void* d_out, int out_size, void* d_ws, size_t ws_size,
                              hipStream_t stream) {
    const float* x    = (const float*)d_in[0];
    const float* W_pc = (const float*)d_in[1];
    const float* b_pc = (const float*)d_in[2];
    const float* W    = (const float*)d_in[3];
    const int* niter  = (const int*)d_in[4];
    float* out = (float*)d_out;

    float4* Wt = (float4*)d_ws;   // 3584 float4 = 57 KB scratch

    int B = in_sizes[0] / 210;
    int elems_per_block = GPB * EPG;
    int blocks = (B + elems_per_block - 1) / elems_per_block;

    transpose_W_kernel<<<14, 256, 0, stream>>>(W, Wt);
    capsnet_kernel<<<blocks, THREADS, 0, stream>>>(x, W_pc, b_pc, Wt, niter, out, B);
}

// Round 9
// 322.442 us; speedup vs baseline: 1.4722x; 1.4722x over previous
//
#include <hip/hip_runtime.h>
#include <math.h>

#define WPB 4        // 64-lane waves per 256-thread block
#define EPW 2        // batch elements per wave
#define THREADS 256

// ---- 16-lane-row sum via DPP row rotates (VALU pipe, no LDS) ----
template<int CTRL>
__device__ __forceinline__ float dpp_add(float x) {
    int xi = __builtin_bit_cast(int, x);
    int yi = __builtin_amdgcn_update_dpp(0, xi, CTRL, 0xF, 0xF, false);
    return x + __builtin_bit_cast(float, yi);
}
__device__ __forceinline__ float row16_sum(float x) {
    x = dpp_add<0x121>(x);  // row_ror:1
    x = dpp_add<0x122>(x);  // row_ror:2
    x = dpp_add<0x124>(x);  // row_ror:4
    x = dpp_add<0x128>(x);  // row_ror:8
    return x;               // every lane in its 16-row holds the row sum
}
// ---- k-reduction across the 4 kq lanes: lane^16 (swizzle) + lane^32 (shfl) ----
__device__ __forceinline__ float kq_sum(float x) {
    int y = __builtin_amdgcn_ds_swizzle(__builtin_bit_cast(int, x), 0x401F); // ^16
    x += __builtin_bit_cast(float, y);
    x += __shfl_xor(x, 32, 64);                                             // ^32
    return x;
}
__device__ __forceinline__ float rcpf_(float x) { return __builtin_amdgcn_rcpf(x); }

// ---- setup: W[7,12,8,16] -> Wt[(n*8+j)*64 + l] float4, l=(kq,t) ----
// lane l: kq=l>>4, t=l&15, m=min(t,11); entry covers k = kq*4 .. kq*4+3
__global__ void transpose_W_kernel(const float* __restrict__ W,
                                   float4* __restrict__ Wt) {
    int i = blockIdx.x * blockDim.x + threadIdx.x;   // 7*8*64 = 3584
    if (i < 3584) {
        int l  = i & 63;
        int r  = i >> 6;          // n*8 + j
        int j  = r & 7;
        int n  = r >> 3;
        int kq = l >> 4;
        int t  = l & 15;
        int mm = (t < 12) ? t : 11;
        const float* src = W + (((size_t)(n * 12 + mm) * 8 + j) * 16 + kq * 4);
        Wt[i] = *(const float4*)src;
    }
}

// One 64-lane wave per 2 batch elements. lane = (kq = k-quarter, t = capsule m).
// Each lane holds u_hat k-quarter fragments for BOTH elements (ILP-2 routing).
__global__ __launch_bounds__(THREADS) void capsnet_kernel(
    const float* __restrict__ x,      // [B,210]
    const float* __restrict__ W_pc,   // [7,8,30]
    const float* __restrict__ b_pc,   // [7,8]
    const float4* __restrict__ Wt,    // transposed W
    const int*  __restrict__ p_niter,
    float* __restrict__ out,          // [B,12]
    int B)
{
    __shared__ float xs[WPB][420];        // two adjacent x rows per wave
    __shared__ float us[WPB][EPW][56];    // primary capsules

    const int tid = threadIdx.x;
    const int w   = tid >> 6;      // wave within block
    const int l   = tid & 63;      // lane within wave
    const int kq  = l >> 4;        // k-quarter: owns k = kq*4 .. kq*4+3
    const int t   = l & 15;        // candidate capsule index
    int b0 = (blockIdx.x * WPB + w) * EPW;
    if (b0 + 1 >= B) b0 = B - 2;   // clamp; duplicates write identical values
    const int niter = *p_niter;

    // ---- stage x[b0], x[b0+1] (contiguous 210 float2) into LDS ----
    {
        const float2* xrow = (const float2*)(x + (size_t)b0 * 210);
        float2* xdst = (float2*)&xs[w][0];
        #pragma unroll
        for (int i = 0; i < 4; ++i) {
            int idx = l + 64 * i;
            if (idx < 210) xdst[idx] = xrow[idx];
        }
    }
    __syncthreads();

    // ---- primary capsules: 112 tasks (2 elems x 56 outputs) over 64 lanes ----
    #pragma unroll
    for (int i = 0; i < 2; ++i) {
        int task = l + 64 * i;
        if (task < 112) {
            int e   = (task >= 56);
            int idx = task - (e ? 56 : 0);    // n*8 + o
            int n   = idx >> 3;
            const float2* wrow2 = (const float2*)(W_pc + idx * 30);
            const float2* xr2   = (const float2*)&xs[w][e * 210 + n * 30];
            float acc = b_pc[idx];
            #pragma unroll
            for (int gg = 0; gg < 15; ++gg) {
                float2 wv = wrow2[gg];
                float2 xv = xr2[gg];
                acc += xv.x * wv.x;
                acc += xv.y * wv.y;
            }
            us[w][e][idx] = acc;
        }
    }
    __syncthreads();

    // ---- squash primary capsules: 14 tasks (2 elems x 7 n) ----
    if (l < 14) {
        int se = (l >= 7);
        int sn = l - (se ? 7 : 0);
        float vals[8];
        float s2 = 0.f;
        #pragma unroll
        for (int o = 0; o < 8; ++o) {
            vals[o] = us[w][se][sn * 8 + o];
            s2 += vals[o] * vals[o];
        }
        float nrm = sqrtf(s2);
        float f = nrm * rcpf_((1.f + s2) * (nrm + 1e-8f));
        #pragma unroll
        for (int o = 0; o < 8; ++o) us[w][se][sn * 8 + o] = vals[o] * f;
    }
    __syncthreads();

    // ---- u_hat[e][n][kk]: one float4 load per (n,j), shared by both elems ----
    float uh[EPW][7][4];
    #pragma unroll
    for (int n = 0; n < 7; ++n) {
        float uu[EPW][8];
        #pragma unroll
        for (int e = 0; e < EPW; ++e) {
            float4 a  = *(const float4*)&us[w][e][n * 8];
            float4 c4 = *(const float4*)&us[w][e][n * 8 + 4];
            uu[e][0] = a.x;  uu[e][1] = a.y;  uu[e][2] = a.z;  uu[e][3] = a.w;
            uu[e][4] = c4.x; uu[e][5] = c4.y; uu[e][6] = c4.z; uu[e][7] = c4.w;
        }
        #pragma unroll
        for (int e = 0; e < EPW; ++e)
            #pragma unroll
            for (int kk = 0; kk < 4; ++kk) uh[e][n][kk] = 0.f;
        #pragma unroll
        for (int j = 0; j < 8; ++j) {
            float4 wv = Wt[(size_t)(n * 8 + j) * 64 + l];   // k = kq*4 .. +3
            #pragma unroll
            for (int e = 0; e < EPW; ++e) {
                float uj = uu[e][j];
                uh[e][n][0] += uj * wv.x;  uh[e][n][1] += uj * wv.y;
                uh[e][n][2] += uj * wv.z;  uh[e][n][3] += uj * wv.w;
            }
        }
    }

    // ---- dynamic routing: two independent chains (ILP-2) ----
    const bool active = (t < 12);
    float blog[EPW][7];
    float vnorm[EPW];
    #pragma unroll
    for (int e = 0; e < EPW; ++e) vnorm[e] = 0.f;

    // iteration 0: b == 0 => c == 1/12 exactly
    {
        float s[EPW][4];
        #pragma unroll
        for (int e = 0; e < EPW; ++e) {
            #pragma unroll
            for (int kk = 0; kk < 4; ++kk) s[e][kk] = uh[e][0][kk];
            #pragma unroll
            for (int n = 1; n < 7; ++n)
                #pragma unroll
                for (int kk = 0; kk < 4; ++kk) s[e][kk] += uh[e][n][kk];
            const float c0 = 1.0f / 12.0f;
            #pragma unroll
            for (int kk = 0; kk < 4; ++kk) s[e][kk] *= c0;
        }
        #pragma unroll
        for (int e = 0; e < EPW; ++e) {
            float s2l = 0.f;
            #pragma unroll
            for (int kk = 0; kk < 4; ++kk) s2l += s[e][kk] * s[e][kk];
            float s2 = kq_sum(s2l);                   // full 16-k norm^2
            float nrm = sqrtf(s2);
            float f = nrm * rcpf_((1.f + s2) * (nrm + 1e-8f));
            if (niter == 1) {
                vnorm[e] = f * nrm;
            } else {
                #pragma unroll
                for (int kk = 0; kk < 4; ++kk) s[e][kk] *= f;  // s -> v
                #pragma unroll
                for (int n = 0; n < 7; ++n) {
                    float dl = 0.f;
                    #pragma unroll
                    for (int kk = 0; kk < 4; ++kk) dl += uh[e][n][kk] * s[e][kk];
                    blog[e][n] = kq_sum(dl);
                }
            }
        }
    }

    for (int it = 1; it < niter; ++it) {
        #pragma unroll
        for (int e = 0; e < EPW; ++e) {
            float c[7];
            #pragma unroll
            for (int n = 0; n < 7; ++n) {
                float ev = active ? __expf(blog[e][n]) : 0.f;
                float sm = row16_sum(ev);
                c[n] = ev * rcpf_(sm);
            }
            float s[4];
            #pragma unroll
            for (int kk = 0; kk < 4; ++kk) s[kk] = 0.f;
            #pragma unroll
            for (int n = 0; n < 7; ++n) {
                float cn = c[n];
                #pragma unroll
                for (int kk = 0; kk < 4; ++kk) s[kk] += cn * uh[e][n][kk];
            }
            float s2l = 0.f;
            #pragma unroll
            for (int kk = 0; kk < 4; ++kk) s2l += s[kk] * s[kk];
            float s2 = kq_sum(s2l);
            float nrm = sqrtf(s2);
            float f = nrm * rcpf_((1.f + s2) * (nrm + 1e-8f));
            if (it == niter - 1) {
                vnorm[e] = f * nrm;
            } else {
                #pragma unroll
                for (int kk = 0; kk < 4; ++kk) s[kk] *= f;    // s -> v
                #pragma unroll
                for (int n = 0; n < 7; ++n) {
                    float dl = 0.f;
                    #pragma unroll
                    for (int kk = 0; kk < 4; ++kk) dl += uh[e][n][kk] * s[kk];
                    blog[e][n] += kq_sum(dl);
                }
            }
        }
    }

    if (active && (kq == 0)) {
        #pragma unroll
        for (int e = 0; e < EPW; ++e)
            out[(size_t)(b0 + e) * 12 + t] = vnorm[e];
    }
}

extern "C" void kernel_launch(void* const* d_in, const int* in_sizes, int n_in,
                              void* d_out, int out_size, void* d_ws, size_t ws_size,
                              hipStream_t stream) {
    const float* x    = (const float*)d_in[0];
    const float* W_pc = (const float*)d_in[1];
    const float* b_pc = (const float*)d_in[2];
    const float* W    = (const float*)d_in[3];
    const int* niter  = (const int*)d_in[4];
    float* out = (float*)d_out;

    float4* Wt = (float4*)d_ws;   // 3584 float4 = 57 KB scratch

    int B = in_sizes[0] / 210;
    int elems_per_block = WPB * EPW;
    int blocks = (B + elems_per_block - 1) / elems_per_block;

    transpose_W_kernel<<<14, 256, 0, stream>>>(W, Wt);
    capsnet_kernel<<<blocks, THREADS, 0, stream>>>(x, W_pc, b_pc, Wt, niter, out, B);
}

// Round 10
// 218.875 us; speedup vs baseline: 2.1688x; 1.4732x over previous
//
#include <hip/hip_runtime.h>
#include <math.h>

#define WPB 4        // 64-lane waves per 256-thread block; 1 batch element per wave
#define THREADS 256

// ---- 16-lane-row sum via DPP row rotates (VALU pipe, no LDS) ----
template<int CTRL>
__device__ __forceinline__ float dpp_add(float x) {
    int xi = __builtin_bit_cast(int, x);
    int yi = __builtin_amdgcn_update_dpp(0, xi, CTRL, 0xF, 0xF, false);
    return x + __builtin_bit_cast(float, yi);
}
__device__ __forceinline__ float row16_sum(float x) {
    x = dpp_add<0x121>(x);  // row_ror:1
    x = dpp_add<0x122>(x);  // row_ror:2
    x = dpp_add<0x124>(x);  // row_ror:4
    x = dpp_add<0x128>(x);  // row_ror:8
    return x;               // every lane in its 16-row holds the row sum
}
// ---- k-reduction across the 4 kq lanes: lane^16 (swizzle) + lane^32 (shfl) ----
__device__ __forceinline__ float kq_sum(float x) {
    int y = __builtin_amdgcn_ds_swizzle(__builtin_bit_cast(int, x), 0x401F); // ^16
    x += __builtin_bit_cast(float, y);
    x += __shfl_xor(x, 32, 64);                                             // ^32
    return x;
}
__device__ __forceinline__ float rcpf_(float x) { return __builtin_amdgcn_rcpf(x); }

// ---- setup: W[7,12,8,16] -> Wt[(n*8+j)*64 + l] float4, l=(kq,t) ----
// lane l: kq=l>>4, t=l&15, m=min(t,11); entry covers k = kq*4 .. kq*4+3
__global__ void transpose_W_kernel(const float* __restrict__ W,
                                   float4* __restrict__ Wt) {
    int i = blockIdx.x * blockDim.x + threadIdx.x;   // 7*8*64 = 3584
    if (i < 3584) {
        int l  = i & 63;
        int r  = i >> 6;          // n*8 + j
        int j  = r & 7;
        int n  = r >> 3;
        int kq = l >> 4;
        int t  = l & 15;
        int mm = (t < 12) ? t : 11;
        const float* src = W + (((size_t)(n * 12 + mm) * 8 + j) * 16 + kq * 4);
        Wt[i] = *(const float4*)src;
    }
}

// One 64-lane wave per batch element. lane = (kq = k-quarter, t = capsule m).
// Minimal per-lane state (uh[7][4]=28 regs) to maximize resident waves.
__global__ __launch_bounds__(THREADS) void capsnet_kernel(
    const float* __restrict__ x,      // [B,210]
    const float* __restrict__ W_pc,   // [7,8,30]
    const float* __restrict__ b_pc,   // [7,8]
    const float4* __restrict__ Wt,    // transposed W
    const int*  __restrict__ p_niter,
    float* __restrict__ out,          // [B,12]
    int B)
{
    __shared__ float xs[WPB][210];    // one x row per wave
    __shared__ float us[WPB][56];     // primary capsules

    const int tid = threadIdx.x;
    const int w   = tid >> 6;      // wave within block
    const int l   = tid & 63;      // lane within wave
    const int kq  = l >> 4;        // k-quarter: owns k = kq*4 .. kq*4+3
    const int t   = l & 15;        // candidate capsule index
    int b = blockIdx.x * WPB + w;
    const bool valid_b = (b < B);
    if (!valid_b) b = B - 1;       // clamp: compute redundantly, skip store
    const int niter = *p_niter;

    // ---- stage x[b] into LDS (105 float2 over 64 lanes) ----
    {
        const float2* xrow = (const float2*)(x + (size_t)b * 210);
        float2* xdst = (float2*)&xs[w][0];
        #pragma unroll
        for (int i = 0; i < 2; ++i) {
            int idx = l + 64 * i;
            if (idx < 105) xdst[idx] = xrow[idx];
        }
    }
    __syncthreads();

    // ---- primary capsules: 56 outputs over 64 lanes (1 round) ----
    if (l < 56) {
        int n = l >> 3;
        const float2* wrow2 = (const float2*)(W_pc + l * 30);
        const float2* xr2   = (const float2*)&xs[w][n * 30];
        float acc = b_pc[l];
        #pragma unroll
        for (int gg = 0; gg < 15; ++gg) {
            float2 wv = wrow2[gg];
            float2 xv = xr2[gg];
            acc += xv.x * wv.x;
            acc += xv.y * wv.y;
        }
        us[w][l] = acc;
    }
    __syncthreads();

    // ---- squash primary capsules (lanes 0..6, one n each) ----
    if (l < 7) {
        float vals[8];
        float s2 = 0.f;
        #pragma unroll
        for (int o = 0; o < 8; ++o) {
            vals[o] = us[w][l * 8 + o];
            s2 += vals[o] * vals[o];
        }
        float nrm = sqrtf(s2);
        float f = nrm * rcpf_((1.f + s2) * (nrm + 1e-8f));
        #pragma unroll
        for (int o = 0; o < 8; ++o) us[w][l * 8 + o] = vals[o] * f;
    }
    __syncthreads();

    // ---- u_hat[n][kk] = sum_j u[n][j] * W[n][m=t][j][kq*4+kk] ----
    float uh[7][4];
    #pragma unroll
    for (int n = 0; n < 7; ++n) {
        float uu[8];
        {
            float4 a  = *(const float4*)&us[w][n * 8];
            float4 c4 = *(const float4*)&us[w][n * 8 + 4];
            uu[0] = a.x;  uu[1] = a.y;  uu[2] = a.z;  uu[3] = a.w;
            uu[4] = c4.x; uu[5] = c4.y; uu[6] = c4.z; uu[7] = c4.w;
        }
        #pragma unroll
        for (int kk = 0; kk < 4; ++kk) uh[n][kk] = 0.f;
        #pragma unroll
        for (int j = 0; j < 8; ++j) {
            float4 wv = Wt[(size_t)(n * 8 + j) * 64 + l];   // k = kq*4 .. +3
            float uj = uu[j];
            uh[n][0] += uj * wv.x;  uh[n][1] += uj * wv.y;
            uh[n][2] += uj * wv.z;  uh[n][3] += uj * wv.w;
        }
    }

    // ---- dynamic routing ----
    const bool active = (t < 12);
    float blog[7];
    float vnorm = 0.f;

    // iteration 0: b == 0 => c == 1/12 exactly (softmax of zeros)
    {
        float s[4];
        #pragma unroll
        for (int kk = 0; kk < 4; ++kk) s[kk] = uh[0][kk];
        #pragma unroll
        for (int n = 1; n < 7; ++n)
            #pragma unroll
            for (int kk = 0; kk < 4; ++kk) s[kk] += uh[n][kk];
        const float c0 = 1.0f / 12.0f;
        #pragma unroll
        for (int kk = 0; kk < 4; ++kk) s[kk] *= c0;
        float s2l = 0.f;
        #pragma unroll
        for (int kk = 0; kk < 4; ++kk) s2l += s[kk] * s[kk];
        float s2 = kq_sum(s2l);            // full 16-k norm^2
        float nrm = sqrtf(s2);
        float f = nrm * rcpf_((1.f + s2) * (nrm + 1e-8f));
        if (niter == 1) {
            vnorm = f * nrm;
        } else {
            #pragma unroll
            for (int kk = 0; kk < 4; ++kk) s[kk] *= f;   // s -> v (my k-quarter)
            #pragma unroll
            for (int n = 0; n < 7; ++n) {
                float dl = 0.f;
                #pragma unroll
                for (int kk = 0; kk < 4; ++kk) dl += uh[n][kk] * s[kk];
                blog[n] = kq_sum(dl);       // full dot over 16 k
            }
        }
    }

    for (int it = 1; it < niter; ++it) {
        // softmax over m within each 16-lane row (no max-sub: logits bounded;
        // inactive lanes contribute exp=0). All 4 kq rows compute identically.
        float c[7];
        #pragma unroll
        for (int n = 0; n < 7; ++n) {
            float ev = active ? __expf(blog[n]) : 0.f;
            float sm = row16_sum(ev);
            c[n] = ev * rcpf_(sm);
        }
        float s[4];
        #pragma unroll
        for (int kk = 0; kk < 4; ++kk) s[kk] = 0.f;
        #pragma unroll
        for (int n = 0; n < 7; ++n) {
            float cn = c[n];
            #pragma unroll
            for (int kk = 0; kk < 4; ++kk) s[kk] += cn * uh[n][kk];
        }
        float s2l = 0.f;
        #pragma unroll
        for (int kk = 0; kk < 4; ++kk) s2l += s[kk] * s[kk];
        float s2 = kq_sum(s2l);
        float nrm = sqrtf(s2);
        float f = nrm * rcpf_((1.f + s2) * (nrm + 1e-8f));
        if (it == niter - 1) {
            vnorm = f * nrm;
        } else {
            #pragma unroll
            for (int kk = 0; kk < 4; ++kk) s[kk] *= f;   // s -> v
            #pragma unroll
            for (int n = 0; n < 7; ++n) {
                float dl = 0.f;
                #pragma unroll
                for (int kk = 0; kk < 4; ++kk) dl += uh[n][kk] * s[kk];
                blog[n] += kq_sum(dl);
            }
        }
    }

    if (active && (kq == 0) && valid_b) out[(size_t)b * 12 + t] = vnorm;
}

extern "C" void kernel_launch(void* const* d_in, const int* in_sizes, int n_in,
                              void* d_out, int out_size, void* d_ws, size_t ws_size,
                              hipStream_t stream) {
    const float* x    = (const float*)d_in[0];
    const float* W_pc = (const float*)d_in[1];
    const float* b_pc = (const float*)d_in[2];
    const float* W    = (const float*)d_in[3];
    const int* niter  = (const int*)d_in[4];
    float* out = (float*)d_out;

    float4* Wt = (float4*)d_ws;   // 3584 float4 = 57 KB scratch

    int B = in_sizes[0] / 210;
    int blocks = (B + WPB - 1) / WPB;

    transpose_W_kernel<<<14, 256, 0, stream>>>(W, Wt);
    capsnet_kernel<<<blocks, THREADS, 0, stream>>>(x, W_pc, b_pc, Wt, niter, out, B);
}

// Round 13
// 207.905 us; speedup vs baseline: 2.2833x; 1.0528x over previous
//
#include <hip/hip_runtime.h>
#include <math.h>

#define THREADS 1024
#define WPB 16       // 16 waves per block; one batch element per wave

// ---- 16-lane-row sum via DPP row rotates (VALU pipe, no LDS) ----
template<int CTRL>
__device__ __forceinline__ float dpp_add(float x) {
    int xi = __builtin_bit_cast(int, x);
    int yi = __builtin_amdgcn_update_dpp(0, xi, CTRL, 0xF, 0xF, false);
    return x + __builtin_bit_cast(float, yi);
}
__device__ __forceinline__ float row16_sum(float x) {
    x = dpp_add<0x121>(x);  // row_ror:1
    x = dpp_add<0x122>(x);  // row_ror:2
    x = dpp_add<0x124>(x);  // row_ror:4
    x = dpp_add<0x128>(x);  // row_ror:8
    return x;               // every lane in its 16-row holds the row sum
}
// ---- k-reduction across the 4 kq lanes: lane^16 (swizzle) + lane^32 (shfl) ----
__device__ __forceinline__ float kq_sum(float x) {
    int y = __builtin_amdgcn_ds_swizzle(__builtin_bit_cast(int, x), 0x401F); // ^16
    x += __builtin_bit_cast(float, y);
    x += __shfl_xor(x, 32, 64);                                             // ^32
    return x;
}
__device__ __forceinline__ float rcpf_(float x) { return __builtin_amdgcn_rcpf(x); }

// One 1024-thread block = 16 waves = 16 batch elements.
// Wt (transposed W, 56 KB) is staged ONCE per block into LDS and reused by all
// 16 elements -> kills the per-element 57 KB L2 re-read that bound R5/R10.
// Per-wave layout (= R10): lane l = (kq = l>>4 k-quarter, t = l&15 capsule m).
__global__ __launch_bounds__(THREADS) void capsnet_kernel(
    const float* __restrict__ x,      // [B,210]
    const float* __restrict__ W_pc,   // [7,8,30]
    const float* __restrict__ b_pc,   // [7,8]
    const float* __restrict__ W,      // [7,12,8,16]
    const int*  __restrict__ p_niter,
    float* __restrict__ out,          // [B,12]
    int B)
{
    __shared__ float4 WtL[3584];      // Wt[(n*8+j)*64 + l], l=(kq,t): 56 KB
    __shared__ float  xs[WPB][210];   // one x row per wave: 13.4 KB
    __shared__ float  us[WPB][56];    // primary capsules: 3.6 KB

    const int tid = threadIdx.x;
    const int w   = tid >> 6;      // wave within block (0..15)
    const int l   = tid & 63;      // lane within wave
    const int kq  = l >> 4;        // k-quarter: owns k = kq*4 .. kq*4+3
    const int t   = l & 15;        // candidate capsule index
    int b = blockIdx.x * WPB + w;
    const bool valid_b = (b < B);
    if (!valid_b) b = B - 1;       // clamp: compute redundantly, skip store
    const int niter = *p_niter;

    // ---- stage Wt into LDS (transpose folded in; 3584 float4 over 1024 thr) ----
    #pragma unroll
    for (int rep = 0; rep < 4; ++rep) {
        int i = tid + THREADS * rep;
        if (i < 3584) {
            int lL  = i & 63;
            int r   = i >> 6;          // n*8 + j
            int j   = r & 7;
            int n   = r >> 3;
            int kqL = lL >> 4;
            int tL  = lL & 15;
            int mm  = (tL < 12) ? tL : 11;
            WtL[i] = *(const float4*)(W + (((size_t)(n * 12 + mm) * 8 + j) * 16 + kqL * 4));
        }
    }
    // ---- stage x[b] into LDS (105 float2 over this wave's 64 lanes) ----
    {
        const float2* xrow = (const float2*)(x + (size_t)b * 210);
        float2* xdst = (float2*)&xs[w][0];
        #pragma unroll
        for (int i = 0; i < 2; ++i) {
            int idx = l + 64 * i;
            if (idx < 105) xdst[idx] = xrow[idx];
        }
    }
    __syncthreads();

    // ---- primary capsules: 56 outputs over 64 lanes (1 round) ----
    if (l < 56) {
        int n = l >> 3;
        const float2* wrow2 = (const float2*)(W_pc + l * 30);
        const float2* xr2   = (const float2*)&xs[w][n * 30];
        float acc = b_pc[l];
        #pragma unroll
        for (int gg = 0; gg < 15; ++gg) {
            float2 wv = wrow2[gg];
            float2 xv = xr2[gg];
            acc += xv.x * wv.x;
            acc += xv.y * wv.y;
        }
        us[w][l] = acc;
    }
    __syncthreads();

    // ---- squash primary capsules (lanes 0..6 of each wave, one n each) ----
    if (l < 7) {
        float vals[8];
        float s2 = 0.f;
        #pragma unroll
        for (int o = 0; o < 8; ++o) {
            vals[o] = us[w][l * 8 + o];
            s2 += vals[o] * vals[o];
        }
        float nrm = sqrtf(s2);
        float f = nrm * rcpf_((1.f + s2) * (nrm + 1e-8f));
        #pragma unroll
        for (int o = 0; o < 8; ++o) us[w][l * 8 + o] = vals[o] * f;
    }
    __syncthreads();

    // ---- u_hat[n][kk] = sum_j u[n][j] * W[n][m=t][j][kq*4+kk], from LDS ----
    float uh[7][4];
    #pragma unroll
    for (int n = 0; n < 7; ++n) {
        float uu[8];
        {
            float4 a  = *(const float4*)&us[w][n * 8];
            float4 c4 = *(const float4*)&us[w][n * 8 + 4];
            uu[0] = a.x;  uu[1] = a.y;  uu[2] = a.z;  uu[3] = a.w;
            uu[4] = c4.x; uu[5] = c4.y; uu[6] = c4.z; uu[7] = c4.w;
        }
        #pragma unroll
        for (int kk = 0; kk < 4; ++kk) uh[n][kk] = 0.f;
        #pragma unroll
        for (int j = 0; j < 8; ++j) {
            float4 wv = WtL[(n * 8 + j) * 64 + l];   // ds_read_b128, conflict-free
            float uj = uu[j];
            uh[n][0] += uj * wv.x;  uh[n][1] += uj * wv.y;
            uh[n][2] += uj * wv.z;  uh[n][3] += uj * wv.w;
        }
    }

    // ---- dynamic routing ----
    const bool active = (t < 12);
    float blog[7];
    float vnorm = 0.f;

    // iteration 0: b == 0 => c == 1/12 exactly (softmax of zeros)
    {
        float s[4];
        #pragma unroll
        for (int kk = 0; kk < 4; ++kk) s[kk] = uh[0][kk];
        #pragma unroll
        for (int n = 1; n < 7; ++n)
            #pragma unroll
            for (int kk = 0; kk < 4; ++kk) s[kk] += uh[n][kk];
        const float c0 = 1.0f / 12.0f;
        #pragma unroll
        for (int kk = 0; kk < 4; ++kk) s[kk] *= c0;
        float s2l = 0.f;
        #pragma unroll
        for (int kk = 0; kk < 4; ++kk) s2l += s[kk] * s[kk];
        float s2 = kq_sum(s2l);            // full 16-k norm^2
        float nrm = sqrtf(s2);
        float f = nrm * rcpf_((1.f + s2) * (nrm + 1e-8f));
        if (niter == 1) {
            vnorm = f * nrm;
        } else {
            #pragma unroll
            for (int kk = 0; kk < 4; ++kk) s[kk] *= f;   // s -> v (my k-quarter)
            #pragma unroll
            for (int n = 0; n < 7; ++n) {
                float dl = 0.f;
                #pragma unroll
                for (int kk = 0; kk < 4; ++kk) dl += uh[n][kk] * s[kk];
                blog[n] = kq_sum(dl);       // full dot over 16 k
            }
        }
    }

    for (int it = 1; it < niter; ++it) {
        // softmax over m within each 16-lane row (no max-sub: logits bounded;
        // inactive lanes contribute exp=0). All 4 kq rows compute identically.
        float c[7];
        #pragma unroll
        for (int n = 0; n < 7; ++n) {
            float ev = active ? __expf(blog[n]) : 0.f;
            float sm = row16_sum(ev);
            c[n] = ev * rcpf_(sm);
        }
        float s[4];
        #pragma unroll
        for (int kk = 0; kk < 4; ++kk) s[kk] = 0.f;
        #pragma unroll
        for (int n = 0; n < 7; ++n) {
            float cn = c[n];
            #pragma unroll
            for (int kk = 0; kk < 4; ++kk) s[kk] += cn * uh[n][kk];
        }
        float s2l = 0.f;
        #pragma unroll
        for (int kk = 0; kk < 4; ++kk) s2l += s[kk] * s[kk];
        float s2 = kq_sum(s2l);
        float nrm = sqrtf(s2);
        float f = nrm * rcpf_((1.f + s2) * (nrm + 1e-8f));
        if (it == niter - 1) {
            vnorm = f * nrm;
        } else {
            #pragma unroll
            for (int kk = 0; kk < 4; ++kk) s[kk] *= f;   // s -> v
            #pragma unroll
            for (int n = 0; n < 7; ++n) {
                float dl = 0.f;
                #pragma unroll
                for (int kk = 0; kk < 4; ++kk) dl += uh[n][kk] * s[kk];
                blog[n] += kq_sum(dl);
            }
        }
    }

    if (active && (kq == 0) && valid_b) out[(size_t)b * 12 + t] = vnorm;
}

extern "C" void kernel_launch(void* const* d_in, const int* in_sizes, int n_in,
                              void* d_out, int out_size, void* d_ws, size_t ws_size,
                              hipStream_t stream) {
    const float* x    = (const float*)d_in[0];
    const float* W_pc = (const float*)d_in[1];
    const float* b_pc = (const float*)d_in[2];
    const float* W    = (const float*)d_in[3];
    const int* niter  = (const int*)d_in[4];
    float* out = (float*)d_out;

    int B = in_sizes[0] / 210;
    int blocks = (B + WPB - 1) / WPB;

    capsnet_kernel<<<blocks, THREADS, 0, stream>>>(x, W_pc, b_pc, W, niter, out, B);
}